// Round 4
// baseline (342.822 us; speedup 1.0000x reference)
//
#include <hip/hip_runtime.h>
#include <hip/hip_bf16.h>

#define BB 4
#define CMv 256
#define CTv 64
#define CAv 128
#define NTOK 6400
/* 128^-0.5 * log2(e): softmax runs in exp2 domain */
#define QSCL 0.12753102198064644f

typedef unsigned short u16;
typedef __attribute__((ext_vector_type(8))) short sh8;     // 8 bf16
typedef __attribute__((ext_vector_type(4))) float f32x4;
typedef __attribute__((ext_vector_type(16))) float f32x16;
typedef __attribute__((ext_vector_type(4))) unsigned uint4v;

__device__ __forceinline__ u16 f2bf(float f) {
  return __builtin_bit_cast(u16, __float2bfloat16(f));
}
__device__ __forceinline__ unsigned pk2(float a, float b) {
  return ((unsigned)f2bf(b) << 16) | (unsigned)f2bf(a);
}
__device__ __forceinline__ f32x16 zero16() {
  f32x16 z;
#pragma unroll
  for (int i = 0; i < 16; i++) z[i] = 0.f;
  return z;
}
typedef const __attribute__((address_space(1))) unsigned int* gas_p;
typedef __attribute__((address_space(3))) unsigned int* las_p;
__device__ __forceinline__ void gl_lds16(const u16* g, u16* l) {
  __builtin_amdgcn_global_load_lds((gas_p)g, (las_p)l, 16, 0, 0);
}

// ---------------- weight transpose prep ----------------
__global__ __launch_bounds__(256) void prepw(const float* __restrict__ wq,
                                             const float* __restrict__ wk,
                                             const float* __restrict__ wv,
                                             const float* __restrict__ wo,
                                             float* __restrict__ wqT,
                                             float* __restrict__ wkT,
                                             float* __restrict__ wvT,
                                             float* __restrict__ woT) {
  int i0 = blockIdx.x * 256 + threadIdx.x;
  for (int idx = i0; idx < 256 * 128; idx += 32 * 256) {
    int ch = idx & 127, cin = idx >> 7;
    wqT[idx] = wq[ch * CMv + cin];
  }
  for (int idx = i0; idx < 64 * 128; idx += 32 * 256) {
    int ch = idx & 127, cin = idx >> 7;
    wkT[idx] = wk[ch * CTv + cin];
    wvT[idx] = wv[ch * CTv + cin];
  }
  for (int idx = i0; idx < 128 * 256; idx += 32 * 256) {
    int ch = idx & 255, c = idx >> 8;
    woT[idx] = wo[ch * CAv + c];
  }
}

// ---------------- Q projection (scale+log2e folded) ----------------
__global__ __launch_bounds__(256) void qproj(const float* __restrict__ met,
                                             const float* __restrict__ wqT,
                                             const float* __restrict__ bq,
                                             u16* __restrict__ Qtm) {
  const int b = blockIdx.x / 100;
  const int tokb = (blockIdx.x % 100) * 64;
  const int tok = threadIdx.x & 63;
  const int chg = __builtin_amdgcn_readfirstlane(threadIdx.x >> 6);  // 0..3
  const float* wt = wqT + chg * 32;
  const float* mp = met + (size_t)b * CMv * NTOK + tokb + tok;
  float acc[32];
#pragma unroll
  for (int j = 0; j < 32; j++) acc[j] = bq[chg * 32 + j];
#pragma unroll 4
  for (int cin = 0; cin < CMv; cin++) {
    float x = mp[(size_t)cin * NTOK];
#pragma unroll
    for (int j = 0; j < 32; j++) acc[j] = fmaf(wt[cin * CAv + j], x, acc[j]);
  }
  u16* qp = Qtm + ((size_t)b * NTOK + tokb + tok) * CAv + chg * 32;
#pragma unroll
  for (int v = 0; v < 4; v++) {
    sh8 pkv;
#pragma unroll
    for (int e = 0; e < 8; e++) pkv[e] = (short)f2bf(acc[v * 8 + e] * QSCL);
    *(sh8*)(qp + v * 8) = pkv;
  }
}

// ---------------- K,V projections ----------------
__global__ __launch_bounds__(512) void kvproj(const float* __restrict__ ter,
                                              const float* __restrict__ wkT,
                                              const float* __restrict__ bk,
                                              const float* __restrict__ wvT,
                                              const float* __restrict__ bv,
                                              u16* __restrict__ Ktm,
                                              u16* __restrict__ Vcm) {
  const int b = blockIdx.x / 100;
  const int tokb = (blockIdx.x % 100) * 64;
  const int tok = threadIdx.x & 63;
  const int grp = __builtin_amdgcn_readfirstlane(threadIdx.x >> 6);  // 0..7
  const bool isV = grp >= 4;
  const int chg = isV ? (grp - 4) : grp;
  const float* wt = (isV ? wvT : wkT) + chg * 32;
  const float* bias = isV ? bv : bk;
  const float* tp = ter + (size_t)b * CTv * NTOK + tokb + tok;
  float acc[32];
#pragma unroll
  for (int j = 0; j < 32; j++) acc[j] = bias[chg * 32 + j];
#pragma unroll 4
  for (int cin = 0; cin < CTv; cin++) {
    float x = tp[(size_t)cin * NTOK];
#pragma unroll
    for (int j = 0; j < 32; j++) acc[j] = fmaf(wt[cin * CAv + j], x, acc[j]);
  }
  if (!isV) {
    u16* kp = Ktm + ((size_t)b * NTOK + tokb + tok) * CAv + chg * 32;
#pragma unroll
    for (int v = 0; v < 4; v++) {
      sh8 pkv;
#pragma unroll
      for (int e = 0; e < 8; e++) pkv[e] = (short)f2bf(acc[v * 8 + e]);
      *(sh8*)(kp + v * 8) = pkv;
    }
  } else {
    u16* vp = Vcm + ((size_t)b * CAv + chg * 32) * NTOK + tokb + tok;
#pragma unroll
    for (int j = 0; j < 32; j++) vp[(size_t)j * NTOK] = f2bf(acc[j]);
  }
}

// ---------------- flash attention ----------------
// 800 blocks = B x 200 q-blocks of 32 rows; 4 waves = 4-way KV split, KVBLK=32.
// V-LDS slices are WAVE-PRIVATE (own DMA, own reads) -> NO barriers in the
// main loop; counted s_waitcnt vmcnt(N) only (T4). In-order vmem queue per
// iter: [V-DMA(t+1) 8][K(t+1) 8]; QK's auto-wait on K(t) retires V-DMA(t)
// (older); vmcnt(16) fence before PV guarantees it under any scheduling
// (vmcnt(8) on the last iter where no t+1 ops are issued).
// V slot swizzle: slot = octet ^ ((c>>1)&3) -> bank-group (c&1)*4+slot is a
// bijection over 8 groups per 8 lanes: conflict-free b128 reads.
__global__ __launch_bounds__(256, 2) void attn(const u16* __restrict__ Qtm,
                                               const u16* __restrict__ Ktm,
                                               const u16* __restrict__ Vcm,
                                               float* __restrict__ Otm) {
  __shared__ __align__(16) unsigned char smem[65536];  // V [2 buf][4 ks][8KB]

  const int tid = threadIdx.x;
  const int ks = tid >> 6;       // wave id = KV split 0..3
  const int lane = tid & 63;
  const int l31 = lane & 31;
  const int h = lane >> 5;

  const int bs = (blockIdx.x & 7) * 100 + (blockIdx.x >> 3);  // XCD swizzle
  const int b = bs / 200;
  const int qb0 = (bs % 200) * 32;

  const u16* Qb = Qtm + ((size_t)b * NTOK + qb0 + l31) * CAv;
  const u16* Kb = Ktm + (size_t)b * NTOK * CAv;
  const u16* Vb = Vcm + (size_t)b * CAv * NTOK;
  const int kv00 = ks * 1600;

  // Q fragments (B-operand): col=q=l31, k = kk*16 + 8h + j
  sh8 qf[8];
#pragma unroll
  for (int kk = 0; kk < 8; kk++) qf[kk] = *(const sh8*)(Qb + kk * 16 + h * 8);

  // K fragments (A-operand): row=kv=l31, k = kk*16 + 8h + j; prefetched
  const u16* kp = Kb + ((size_t)(kv00 + l31)) * CAv + h * 8;
  sh8 kf[8];
#pragma unroll
  for (int kk = 0; kk < 8; kk++) kf[kk] = *(const sh8*)(kp + kk * 16);
  kp += 32 * CAv;

  // V DMA per-lane source: c = j*16 + (lane>>2), slot = lane&3,
  // content octet = slot ^ ((c>>1)&3) = (lane&3) ^ ((lane>>3)&3)
  const u16* vsrc = Vb + (size_t)(lane >> 2) * NTOK + kv00 +
                    (((lane & 3) ^ ((lane >> 3) & 3)) * 8);

  // DMA tile 0 -> buf 0 (issued AFTER K loads: queue order [K(0)][DMA(0)])
  {
    u16* db = (u16*)(smem + ks * 8192);
#pragma unroll
    for (int j = 0; j < 8; j++)
      gl_lds16(vsrc + (size_t)j * 16 * NTOK, db + j * 512);
    vsrc += 32;
  }

  f32x16 o[4];
#pragma unroll
  for (int i = 0; i < 4; i++) o[i] = zero16();
  float m = -1e30f, lsum = 0.f;

  // swizzled V-read byte offsets per PV step b2: slot = (2b2+h) ^ ((l31>>1)&3)
  int voff[2];
#pragma unroll
  for (int b2 = 0; b2 < 2; b2++)
    voff[b2] = l31 * 64 + (((2 * b2 + h) ^ ((l31 >> 1) & 3)) * 16);

  int cur = 0;
  for (int t = 0; t < 50; t++) {
    // issue V DMA for t+1 into other buffer (wave-private slice)
    if (t < 49) {
      u16* db = (u16*)(smem + (cur ^ 1) * 32768 + ks * 8192);
#pragma unroll
      for (int j = 0; j < 8; j++)
        gl_lds16(vsrc + (size_t)j * 16 * NTOK, db + j * 512);
      vsrc += 32;
    }
    // QK^T (S^T): one 32kv x 32q subtile (auto vmcnt wait on kf)
    __builtin_amdgcn_s_setprio(1);
    f32x16 s0 = zero16();
#pragma unroll
    for (int kk = 0; kk < 8; kk++)
      s0 = __builtin_amdgcn_mfma_f32_32x32x16_bf16(kf[kk], qf[kk], s0, 0, 0, 0);
    __builtin_amdgcn_s_setprio(0);
    // prefetch K for t+1
    if (t < 49) {
#pragma unroll
      for (int kk = 0; kk < 8; kk++) kf[kk] = *(const sh8*)(kp + kk * 16);
      kp += 32 * CAv;
    }
    // online softmax, exp2 domain (q lane-local; one xor32 hop)
    float pmax = -1e30f;
#pragma unroll
    for (int r = 0; r < 16; r++) pmax = fmaxf(pmax, s0[r]);
    pmax = fmaxf(pmax, __shfl_xor(pmax, 32));
    if (__any(pmax > m + 8.f)) {  // defer-max: P bounded by 2^8
      float mnew = fmaxf(m, pmax);
      float al = __builtin_exp2f(m - mnew);
#pragma unroll
      for (int i = 0; i < 16; i++) {
        o[0][i] *= al; o[1][i] *= al; o[2][i] *= al; o[3][i] *= al;
      }
      lsum *= al;
      m = mnew;
    }
    f32x16 p;
#pragma unroll
    for (int r = 0; r < 16; r++) p[r] = __builtin_exp2f(s0[r] - m);
    float ps = 0.f;
#pragma unroll
    for (int r = 0; r < 16; r++) ps += p[r];
    ps += __shfl_xor(ps, 32);
    lsum += ps;
    // pack P: pkm[rq][w] holds kv rows 8*rq + 4h + {0..3}
    unsigned pkm[4][2];
#pragma unroll
    for (int rq = 0; rq < 4; rq++) {
      pkm[rq][0] = pk2(p[4 * rq + 0], p[4 * rq + 1]);
      pkm[rq][1] = pk2(p[4 * rq + 2], p[4 * rq + 3]);
    }
    // counted fence: V-DMA(t) is the oldest outstanding group; >=16 younger
    // ops exist (DMA(t+1)+K(t+1)) except at t=49 where it's 8 (K(49)).
    if (t < 49) {
      asm volatile("s_waitcnt vmcnt(16)" ::: "memory");
    } else {
      asm volatile("s_waitcnt vmcnt(8)" ::: "memory");
    }
    // PV: per 16-kv step build B-frag (half local, half via xor-32)
    const unsigned char* vbuf = smem + cur * 32768 + ks * 8192;
#pragma unroll
    for (int b2 = 0; b2 < 2; b2++) {
      unsigned ow0 = h ? pkm[2 * b2 + 1][0] : pkm[2 * b2][0];
      unsigned ow1 = h ? pkm[2 * b2 + 1][1] : pkm[2 * b2][1];
      unsigned sd0 = h ? pkm[2 * b2][0] : pkm[2 * b2 + 1][0];
      unsigned sd1 = h ? pkm[2 * b2][1] : pkm[2 * b2 + 1][1];
      unsigned rv0 = (unsigned)__shfl_xor((int)sd0, 32);
      unsigned rv1 = (unsigned)__shfl_xor((int)sd1, 32);
      uint4v fw = {h ? rv0 : ow0, h ? rv1 : ow1, h ? ow0 : rv0, h ? ow1 : rv1};
      sh8 pf = __builtin_bit_cast(sh8, fw);
      __builtin_amdgcn_s_setprio(1);
#pragma unroll
      for (int ct = 0; ct < 4; ct++) {
        sh8 vf = *(const sh8*)(vbuf + ct * 2048 + voff[b2]);
        o[ct] = __builtin_amdgcn_mfma_f32_32x32x16_bf16(vf, pf, o[ct], 0, 0, 0);
      }
      __builtin_amdgcn_s_setprio(0);
    }
    cur ^= 1;
  }

  // ---- 4-way KV merge, 2-stage tree (aliases V region) ----
  float* OM0 = (float*)smem;                    // [32][132] f32
  float* OM1 = (float*)(smem + 16896);          // [32][132] f32
  float* MLs = (float*)(smem + 33792);          // [slot][{m,l}][32]
  asm volatile("s_waitcnt vmcnt(0)" ::: "memory");
  __syncthreads();  // all waves done with V region before aliasing
  if (ks == 1 || ks == 3) {
    float* om = (ks == 1) ? OM0 : OM1;
    float* ml = MLs + ((ks == 1) ? 0 : 64);
#pragma unroll
    for (int ct = 0; ct < 4; ct++)
#pragma unroll
      for (int rq = 0; rq < 4; rq++) {
        f32x4 v = {o[ct][4 * rq + 0], o[ct][4 * rq + 1],
                   o[ct][4 * rq + 2], o[ct][4 * rq + 3]};
        *(f32x4*)(om + l31 * 132 + ct * 32 + rq * 8 + h * 4) = v;
      }
    if (h == 0) { ml[l31] = m; ml[32 + l31] = lsum; }
  }
  __syncthreads();
  if (ks == 0 || ks == 2) {
    float* om = (ks == 0) ? OM0 : OM1;
    float* ml = MLs + ((ks == 0) ? 0 : 64);
    float m1 = ml[l31], l1 = ml[32 + l31];
    float mM = fmaxf(m, m1);
    float a0 = __builtin_exp2f(m - mM), a1 = __builtin_exp2f(m1 - mM);
#pragma unroll
    for (int ct = 0; ct < 4; ct++)
#pragma unroll
      for (int rq = 0; rq < 4; rq++) {
        f32x4 u = *(const f32x4*)(om + l31 * 132 + ct * 32 + rq * 8 + h * 4);
#pragma unroll
        for (int i = 0; i < 4; i++)
          o[ct][4 * rq + i] = o[ct][4 * rq + i] * a0 + u[i] * a1;
      }
    lsum = lsum * a0 + l1 * a1;
    m = mM;
  }
  __syncthreads();
  if (ks == 2) {  // republish combined (2,3) into slot 1
#pragma unroll
    for (int ct = 0; ct < 4; ct++)
#pragma unroll
      for (int rq = 0; rq < 4; rq++) {
        f32x4 v = {o[ct][4 * rq + 0], o[ct][4 * rq + 1],
                   o[ct][4 * rq + 2], o[ct][4 * rq + 3]};
        *(f32x4*)(OM1 + l31 * 132 + ct * 32 + rq * 8 + h * 4) = v;
      }
    if (h == 0) { MLs[64 + l31] = m; MLs[64 + 32 + l31] = lsum; }
  }
  __syncthreads();
  if (ks == 0) {  // final combine + normalized store
    float m1 = MLs[64 + l31], l1 = MLs[64 + 32 + l31];
    float mM = fmaxf(m, m1);
    float a0 = __builtin_exp2f(m - mM), a1 = __builtin_exp2f(m1 - mM);
    float L = lsum * a0 + l1 * a1;
    float f0 = a0 / L, f1 = a1 / L;
    float* op = Otm + ((size_t)b * NTOK + qb0 + l31) * CAv;
#pragma unroll
    for (int ct = 0; ct < 4; ct++)
#pragma unroll
      for (int rq = 0; rq < 4; rq++) {
        f32x4 u = *(const f32x4*)(OM1 + l31 * 132 + ct * 32 + rq * 8 + h * 4);
        f32x4 w;
#pragma unroll
        for (int i = 0; i < 4; i++)
          w[i] = o[ct][4 * rq + i] * f0 + u[i] * f1;
        *(f32x4*)(op + ct * 32 + rq * 8 + h * 4) = w;
      }
  }
}

// ---------------- output projection + residual ----------------
__global__ __launch_bounds__(512) void outproj(const float* __restrict__ met,
                                               const float* __restrict__ woT,
                                               const float* __restrict__ bo,
                                               const float* __restrict__ Otm,
                                               float* __restrict__ out) {
  const int bs = (blockIdx.x & 7) * 50 + (blockIdx.x >> 3);
  const int b = bs / 100;
  const int tokb = (bs % 100) * 64;
  const int tok = threadIdx.x & 63;
  const int chg = __builtin_amdgcn_readfirstlane(threadIdx.x >> 6);  // 0..7
  const float* op = Otm + ((size_t)b * NTOK + tokb + tok) * CAv;
  float acc[32];
#pragma unroll
  for (int j = 0; j < 32; j++) acc[j] = 0.f;
#pragma unroll 4
  for (int c = 0; c < CAv; c++) {
    float ov = op[c];
    const float* wt = woT + c * CMv + chg * 32;
#pragma unroll
    for (int j = 0; j < 32; j++) acc[j] = fmaf(wt[j], ov, acc[j]);
  }
#pragma unroll
  for (int j = 0; j < 32; j++) {
    int ch = chg * 32 + j;
    size_t idx = ((size_t)b * CMv + ch) * NTOK + tokb + tok;
    out[idx] = met[idx] + acc[j] + bo[ch];
  }
}

extern "C" void kernel_launch(void* const* d_in, const int* in_sizes, int n_in,
                              void* d_out, int out_size, void* d_ws, size_t ws_size,
                              hipStream_t stream) {
  const float* met = (const float*)d_in[0];
  const float* ter = (const float*)d_in[1];
  const float* wq = (const float*)d_in[2];
  const float* bq = (const float*)d_in[3];
  const float* wk = (const float*)d_in[4];
  const float* bk = (const float*)d_in[5];
  const float* wv = (const float*)d_in[6];
  const float* bv = (const float*)d_in[7];
  const float* wo = (const float*)d_in[8];
  const float* bo = (const float*)d_in[9];
  float* out = (float*)d_out;

  u16* Qtm = (u16*)d_ws;
  u16* Ktm = Qtm + (size_t)BB * NTOK * CAv;
  u16* Vcm = Ktm + (size_t)BB * NTOK * CAv;
  float* Otm = (float*)(Vcm + (size_t)BB * NTOK * CAv);
  float* wqT = Otm + (size_t)BB * NTOK * CAv;
  float* wkT = wqT + 256 * 128;
  float* wvT = wkT + 64 * 128;
  float* woT = wvT + 64 * 128;

  prepw<<<dim3(32), dim3(256), 0, stream>>>(wq, wk, wv, wo, wqT, wkT, wvT, woT);
  qproj<<<dim3(400), dim3(256), 0, stream>>>(met, wqT, bq, Qtm);
  kvproj<<<dim3(400), dim3(512), 0, stream>>>(ter, wkT, bk, wvT, bv, Ktm, Vcm);
  attn<<<dim3(800), dim3(256), 0, stream>>>(Qtm, Ktm, Vcm, Otm);
  outproj<<<dim3(400), dim3(512), 0, stream>>>(met, woT, bo, Otm, out);
}

// Round 5
// 247.954 us; speedup vs baseline: 1.3826x; 1.3826x over previous
//
#include <hip/hip_runtime.h>
#include <hip/hip_bf16.h>

#define BB 4
#define CMv 256
#define CTv 64
#define CAv 128
#define NTOK 6400
/* 128^-0.5 * log2(e): softmax runs in exp2 domain */
#define QSCL 0.12753102198064644f

typedef unsigned short u16;
typedef __attribute__((ext_vector_type(8))) short sh8;     // 8 bf16
typedef __attribute__((ext_vector_type(4))) float f32x4;
typedef __attribute__((ext_vector_type(16))) float f32x16;
typedef __attribute__((ext_vector_type(4))) unsigned uint4v;
typedef __attribute__((ext_vector_type(2))) unsigned uint2v;

__device__ __forceinline__ u16 f2bf(float f) {
  return __builtin_bit_cast(u16, __float2bfloat16(f));
}
__device__ __forceinline__ float bf2f(u16 x) {
  unsigned u = ((unsigned)x) << 16;
  return __builtin_bit_cast(float, u);
}
__device__ __forceinline__ unsigned pk2(float a, float b) {
  return ((unsigned)f2bf(b) << 16) | (unsigned)f2bf(a);
}
__device__ __forceinline__ f32x16 zero16() {
  f32x16 z;
#pragma unroll
  for (int i = 0; i < 16; i++) z[i] = 0.f;
  return z;
}
typedef const __attribute__((address_space(1))) unsigned int* gas_p;
typedef __attribute__((address_space(3))) unsigned int* las_p;
__device__ __forceinline__ void gl_lds16(const u16* g, u16* l) {
  __builtin_amdgcn_global_load_lds((gas_p)g, (las_p)l, 16, 0, 0);
}

// ---------------- weight transpose prep ----------------
__global__ __launch_bounds__(256) void prepw(const float* __restrict__ wq,
                                             const float* __restrict__ wk,
                                             const float* __restrict__ wv,
                                             const float* __restrict__ wo,
                                             float* __restrict__ wqT,
                                             float* __restrict__ wkT,
                                             float* __restrict__ wvT,
                                             float* __restrict__ woT) {
  int i0 = blockIdx.x * 256 + threadIdx.x;
  for (int idx = i0; idx < 256 * 128; idx += 32 * 256) {
    int ch = idx & 127, cin = idx >> 7;
    wqT[idx] = wq[ch * CMv + cin];
  }
  for (int idx = i0; idx < 64 * 128; idx += 32 * 256) {
    int ch = idx & 127, cin = idx >> 7;
    wkT[idx] = wk[ch * CTv + cin];
    wvT[idx] = wv[ch * CTv + cin];
  }
  for (int idx = i0; idx < 128 * 256; idx += 32 * 256) {
    int ch = idx & 255, c = idx >> 8;
    woT[idx] = wo[ch * CAv + c];
  }
}

// ---------------- Q projection (scale+log2e folded) ----------------
__global__ __launch_bounds__(256) void qproj(const float* __restrict__ met,
                                             const float* __restrict__ wqT,
                                             const float* __restrict__ bq,
                                             u16* __restrict__ Qtm) {
  const int b = blockIdx.x / 100;
  const int tokb = (blockIdx.x % 100) * 64;
  const int tok = threadIdx.x & 63;
  const int chg = __builtin_amdgcn_readfirstlane(threadIdx.x >> 6);  // 0..3
  const float* wt = wqT + chg * 32;
  const float* mp = met + (size_t)b * CMv * NTOK + tokb + tok;
  float acc[32];
#pragma unroll
  for (int j = 0; j < 32; j++) acc[j] = bq[chg * 32 + j];
#pragma unroll 4
  for (int cin = 0; cin < CMv; cin++) {
    float x = mp[(size_t)cin * NTOK];
#pragma unroll
    for (int j = 0; j < 32; j++) acc[j] = fmaf(wt[cin * CAv + j], x, acc[j]);
  }
  u16* qp = Qtm + ((size_t)b * NTOK + tokb + tok) * CAv + chg * 32;
#pragma unroll
  for (int v = 0; v < 4; v++) {
    sh8 pkv;
#pragma unroll
    for (int e = 0; e < 8; e++) pkv[e] = (short)f2bf(acc[v * 8 + e] * QSCL);
    *(sh8*)(qp + v * 8) = pkv;
  }
}

// ---------------- K,V projections ----------------
__global__ __launch_bounds__(512) void kvproj(const float* __restrict__ ter,
                                              const float* __restrict__ wkT,
                                              const float* __restrict__ bk,
                                              const float* __restrict__ wvT,
                                              const float* __restrict__ bv,
                                              u16* __restrict__ Ktm,
                                              u16* __restrict__ Vcm) {
  const int b = blockIdx.x / 100;
  const int tokb = (blockIdx.x % 100) * 64;
  const int tok = threadIdx.x & 63;
  const int grp = __builtin_amdgcn_readfirstlane(threadIdx.x >> 6);  // 0..7
  const bool isV = grp >= 4;
  const int chg = isV ? (grp - 4) : grp;
  const float* wt = (isV ? wvT : wkT) + chg * 32;
  const float* bias = isV ? bv : bk;
  const float* tp = ter + (size_t)b * CTv * NTOK + tokb + tok;
  float acc[32];
#pragma unroll
  for (int j = 0; j < 32; j++) acc[j] = bias[chg * 32 + j];
#pragma unroll 4
  for (int cin = 0; cin < CTv; cin++) {
    float x = tp[(size_t)cin * NTOK];
#pragma unroll
    for (int j = 0; j < 32; j++) acc[j] = fmaf(wt[cin * CAv + j], x, acc[j]);
  }
  if (!isV) {
    u16* kp = Ktm + ((size_t)b * NTOK + tokb + tok) * CAv + chg * 32;
#pragma unroll
    for (int v = 0; v < 4; v++) {
      sh8 pkv;
#pragma unroll
      for (int e = 0; e < 8; e++) pkv[e] = (short)f2bf(acc[v * 8 + e]);
      *(sh8*)(kp + v * 8) = pkv;
    }
  } else {
    u16* vp = Vcm + ((size_t)b * CAv + chg * 32) * NTOK + tokb + tok;
#pragma unroll
    for (int j = 0; j < 32; j++) vp[(size_t)j * NTOK] = f2bf(acc[j]);
  }
}

// ---------------- flash attention ----------------
// Grid 400 = B x 50 q-tiles x 2 kv-halves. Block: 4 waves, each owns 32 q-rows
// (Q_T=128); ALL waves share each 32-kv K/V tile staged in LDS (triple-buffered,
// staged 2 tiles ahead via global_load_lds). One raw s_barrier + counted
// vmcnt(4) per tile -- prefetch queue never drains. K LDS rows XOR-swizzled
// (slot ^= row&7) via pre-swizzled DMA sources; V swizzle identical to R4.
// Partial O (unnormalized, bf16) + m/l stored per kv-half; merged in outproj.
__global__ __launch_bounds__(256, 2) void attn(const u16* __restrict__ Qtm,
                                               const u16* __restrict__ Ktm,
                                               const u16* __restrict__ Vcm,
                                               u16* __restrict__ Opart,
                                               float* __restrict__ Mpart,
                                               float* __restrict__ Lpart) {
  __shared__ __align__(16) unsigned char smem[49152];  // 3 x (K 8KB | V 8KB)

  const int tid = threadIdx.x;
  const int w = tid >> 6;        // q-subtile 0..3
  const int lane = tid & 63;
  const int l31 = lane & 31;
  const int h = lane >> 5;

  const int bs = (blockIdx.x & 7) * 50 + (blockIdx.x >> 3);  // XCD swizzle
  const int b = bs / 100;
  const int rem = bs % 100;
  const int kvh = rem / 50;
  const int qt = rem % 50;
  const int qb0 = qt * 128;
  const int kv00 = kvh * 3200;

  const u16* Qb = Qtm + ((size_t)b * NTOK + qb0 + w * 32 + l31) * CAv;
  const u16* Kb = Ktm + (size_t)b * NTOK * CAv;
  const u16* Vb = Vcm + (size_t)b * CAv * NTOK;

  // Q fragments (B-operand): col=q=l31, k = kk*16 + 8h + j
  sh8 qf[8];
#pragma unroll
  for (int kk = 0; kk < 8; kk++) qf[kk] = *(const sh8*)(Qb + kk * 16 + h * 8);

  // K DMA sources (pre-swizzled: LDS(r,s) holds K[r][8*(s^(r&7))..+8])
  const int kr0 = (w * 2 + 0) * 4 + (lane >> 4);
  const int kr1 = (w * 2 + 1) * 4 + (lane >> 4);
  const u16* ksrc0 = Kb + ((size_t)kv00 + kr0) * CAv + ((lane & 15) ^ (kr0 & 7)) * 8;
  const u16* ksrc1 = Kb + ((size_t)kv00 + kr1) * CAv + ((lane & 15) ^ (kr1 & 7)) * 8;
  // V DMA sources (LDS(c,s) holds V[c][kv0 + 8*(s^((c>>1)&3))..+8])
  const int vc0 = (w * 2 + 0) * 16 + (lane >> 2);
  const int vc1 = (w * 2 + 1) * 16 + (lane >> 2);
  const int vxor = ((lane & 3) ^ ((lane >> 3) & 3)) * 8;
  const u16* vsrc0 = Vb + (size_t)vc0 * NTOK + kv00 + vxor;
  const u16* vsrc1 = Vb + (size_t)vc1 * NTOK + kv00 + vxor;

  // K-frag LDS byte offsets: row l31, slot (2kk+h)^(l31&7)
  int koff[8];
#pragma unroll
  for (int kk = 0; kk < 8; kk++)
    koff[kk] = l31 * 256 + (((2 * kk + h) ^ (l31 & 7)) << 4);
  // V-frag LDS byte offsets (add ct*2048): row ct*32+l31, slot (2b2+h)^((l31>>1)&3)
  int vo2[2];
#pragma unroll
  for (int b2 = 0; b2 < 2; b2++)
    vo2[b2] = l31 * 64 + (((2 * b2 + h) ^ ((l31 >> 1) & 3)) << 4);

#define STAGE(p)                                              \
  do {                                                        \
    u16* kb_ = (u16*)(smem + (p) * 16384) + w * 1024;         \
    gl_lds16(ksrc0, kb_);                                     \
    gl_lds16(ksrc1, kb_ + 512);                               \
    u16* vb_ = (u16*)(smem + (p) * 16384 + 8192) + w * 1024;  \
    gl_lds16(vsrc0, vb_);                                     \
    gl_lds16(vsrc1, vb_ + 512);                               \
    ksrc0 += 32 * CAv; ksrc1 += 32 * CAv;                     \
    vsrc0 += 32; vsrc1 += 32;                                 \
  } while (0)

  // prologue: stage tiles 0,1; confirm tile 0
  STAGE(0);
  STAGE(1);
  asm volatile("s_waitcnt vmcnt(4)" ::: "memory");
  __builtin_amdgcn_s_barrier();

  f32x16 o[4];
#pragma unroll
  for (int i = 0; i < 4; i++) o[i] = zero16();
  float m = -1e30f, lsum = 0.f;

  int pc = 0;
  for (int t = 0; t < 100; t++) {
    int ps = pc + 2; if (ps >= 3) ps -= 3;
    if (t < 98) STAGE(ps);
    const unsigned char* kbuf = smem + pc * 16384;
    const unsigned char* vbuf = smem + pc * 16384 + 8192;
    // QK^T (S^T): A = K rows from LDS, B = Q regs
    __builtin_amdgcn_s_setprio(1);
    f32x16 s0 = zero16();
#pragma unroll
    for (int kk = 0; kk < 8; kk++) {
      sh8 kf = *(const sh8*)(kbuf + koff[kk]);
      s0 = __builtin_amdgcn_mfma_f32_32x32x16_bf16(kf, qf[kk], s0, 0, 0, 0);
    }
    __builtin_amdgcn_s_setprio(0);
    // online softmax, exp2 domain (q lane-local; one xor32 hop)
    float pmax = -1e30f;
#pragma unroll
    for (int r = 0; r < 16; r++) pmax = fmaxf(pmax, s0[r]);
    pmax = fmaxf(pmax, __shfl_xor(pmax, 32));
    if (__any(pmax > m + 8.f)) {  // defer-max: P bounded by 2^8
      float mnew = fmaxf(m, pmax);
      float al = __builtin_exp2f(m - mnew);
#pragma unroll
      for (int i = 0; i < 16; i++) {
        o[0][i] *= al; o[1][i] *= al; o[2][i] *= al; o[3][i] *= al;
      }
      lsum *= al;
      m = mnew;
    }
    f32x16 p;
#pragma unroll
    for (int r = 0; r < 16; r++) p[r] = __builtin_exp2f(s0[r] - m);
    float ps_ = 0.f;
#pragma unroll
    for (int r = 0; r < 16; r++) ps_ += p[r];
    ps_ += __shfl_xor(ps_, 32);
    lsum += ps_;
    // pack P: pkm[rq][wd] holds kv rows 8*rq + 4h + {0..3}
    unsigned pkm[4][2];
#pragma unroll
    for (int rq = 0; rq < 4; rq++) {
      pkm[rq][0] = pk2(p[4 * rq + 0], p[4 * rq + 1]);
      pkm[rq][1] = pk2(p[4 * rq + 2], p[4 * rq + 3]);
    }
    // PV: per 16-kv step build B-frag (half local, half via xor-32)
#pragma unroll
    for (int b2 = 0; b2 < 2; b2++) {
      unsigned ow0 = h ? pkm[2 * b2 + 1][0] : pkm[2 * b2][0];
      unsigned ow1 = h ? pkm[2 * b2 + 1][1] : pkm[2 * b2][1];
      unsigned sd0 = h ? pkm[2 * b2][0] : pkm[2 * b2 + 1][0];
      unsigned sd1 = h ? pkm[2 * b2][1] : pkm[2 * b2 + 1][1];
      unsigned rv0 = (unsigned)__shfl_xor((int)sd0, 32);
      unsigned rv1 = (unsigned)__shfl_xor((int)sd1, 32);
      uint4v fw = {h ? rv0 : ow0, h ? rv1 : ow1, h ? ow0 : rv0, h ? ow1 : rv1};
      sh8 pf = __builtin_bit_cast(sh8, fw);
      __builtin_amdgcn_s_setprio(1);
#pragma unroll
      for (int ct = 0; ct < 4; ct++) {
        sh8 vf = *(const sh8*)(vbuf + ct * 2048 + vo2[b2]);
        o[ct] = __builtin_amdgcn_mfma_f32_32x32x16_bf16(vf, pf, o[ct], 0, 0, 0);
      }
      __builtin_amdgcn_s_setprio(0);
    }
    // confirm tile t+1 for next iter (keep t+2 DMA in flight)
    if (t < 98) {
      asm volatile("s_waitcnt vmcnt(4)" ::: "memory");
    } else {
      asm volatile("s_waitcnt vmcnt(0)" ::: "memory");
    }
    __builtin_amdgcn_s_barrier();
    pc = pc + 1; if (pc >= 3) pc = 0;
  }
#undef STAGE

  // epilogue: store unnormalized partial O (bf16) + m/l
  u16* op = Opart + (((size_t)kvh * BB + b) * NTOK + qb0 + w * 32 + l31) * CAv;
#pragma unroll
  for (int ct = 0; ct < 4; ct++)
#pragma unroll
    for (int rq = 0; rq < 4; rq++) {
      uint2v d = {pk2(o[ct][4 * rq + 0], o[ct][4 * rq + 1]),
                  pk2(o[ct][4 * rq + 2], o[ct][4 * rq + 3])};
      *(uint2v*)(op + ct * 32 + rq * 8 + h * 4) = d;
    }
  if (h == 0) {
    size_t mi = ((size_t)kvh * BB + b) * NTOK + qb0 + w * 32 + l31;
    Mpart[mi] = m;
    Lpart[mi] = lsum;
  }
}

// ---------------- output projection + kv-half merge + residual ----------------
__global__ __launch_bounds__(512) void outproj(const float* __restrict__ met,
                                               const float* __restrict__ woT,
                                               const float* __restrict__ bo,
                                               const u16* __restrict__ Opart,
                                               const float* __restrict__ Mpart,
                                               const float* __restrict__ Lpart,
                                               float* __restrict__ out) {
  const int bs = (blockIdx.x & 7) * 50 + (blockIdx.x >> 3);
  const int b = bs / 100;
  const int tokb = (bs % 100) * 64;
  const int tok = threadIdx.x & 63;
  const int chg = __builtin_amdgcn_readfirstlane(threadIdx.x >> 6);  // 0..7
  const size_t n = (size_t)b * NTOK + tokb + tok;
  // merge weights for the two kv-halves
  float m0 = Mpart[n], m1 = Mpart[(size_t)BB * NTOK + n];
  float l0 = Lpart[n], l1 = Lpart[(size_t)BB * NTOK + n];
  float M = fmaxf(m0, m1);
  float a0 = __builtin_exp2f(m0 - M), a1 = __builtin_exp2f(m1 - M);
  float L = l0 * a0 + l1 * a1;
  float w0 = a0 / L, w1 = a1 / L;
  const u16* o0 = Opart + n * CAv;
  const u16* o1 = Opart + ((size_t)BB * NTOK + n) * CAv;
  float acc[32];
#pragma unroll
  for (int j = 0; j < 32; j++) acc[j] = 0.f;
#pragma unroll 2
  for (int c8 = 0; c8 < 16; c8++) {
    sh8 va = *(const sh8*)(o0 + c8 * 8);
    sh8 vb = *(const sh8*)(o1 + c8 * 8);
#pragma unroll
    for (int e = 0; e < 8; e++) {
      float ov = bf2f((u16)va[e]) * w0 + bf2f((u16)vb[e]) * w1;
      const float* wt = woT + (c8 * 8 + e) * CMv + chg * 32;
#pragma unroll
      for (int j = 0; j < 32; j++) acc[j] = fmaf(wt[j], ov, acc[j]);
    }
  }
#pragma unroll
  for (int j = 0; j < 32; j++) {
    int ch = chg * 32 + j;
    size_t idx = ((size_t)b * CMv + ch) * NTOK + tokb + tok;
    out[idx] = met[idx] + acc[j] + bo[ch];
  }
}

extern "C" void kernel_launch(void* const* d_in, const int* in_sizes, int n_in,
                              void* d_out, int out_size, void* d_ws, size_t ws_size,
                              hipStream_t stream) {
  const float* met = (const float*)d_in[0];
  const float* ter = (const float*)d_in[1];
  const float* wq = (const float*)d_in[2];
  const float* bq = (const float*)d_in[3];
  const float* wk = (const float*)d_in[4];
  const float* bk = (const float*)d_in[5];
  const float* wv = (const float*)d_in[6];
  const float* bv = (const float*)d_in[7];
  const float* wo = (const float*)d_in[8];
  const float* bo = (const float*)d_in[9];
  float* out = (float*)d_out;

  u16* Qtm = (u16*)d_ws;                                  // B*N*CA bf16
  u16* Ktm = Qtm + (size_t)BB * NTOK * CAv;               // B*N*CA bf16
  u16* Vcm = Ktm + (size_t)BB * NTOK * CAv;               // B*CA*N bf16
  u16* Opart = Vcm + (size_t)BB * NTOK * CAv;             // 2*B*N*CA bf16
  float* Mpart = (float*)(Opart + (size_t)2 * BB * NTOK * CAv);  // 2*B*N
  float* Lpart = Mpart + (size_t)2 * BB * NTOK;
  float* wqT = Lpart + (size_t)2 * BB * NTOK;
  float* wkT = wqT + 256 * 128;
  float* wvT = wkT + 64 * 128;
  float* woT = wvT + 64 * 128;

  prepw<<<dim3(32), dim3(256), 0, stream>>>(wq, wk, wv, wo, wqT, wkT, wvT, woT);
  qproj<<<dim3(400), dim3(256), 0, stream>>>(met, wqT, bq, Qtm);
  kvproj<<<dim3(400), dim3(512), 0, stream>>>(ter, wkT, bk, wvT, bv, Ktm, Vcm);
  attn<<<dim3(400), dim3(256), 0, stream>>>(Qtm, Ktm, Vcm, Opart, Mpart, Lpart);
  outproj<<<dim3(400), dim3(512), 0, stream>>>(met, woT, bo, Opart, Mpart, Lpart, out);
}